// Round 4
// baseline (213.712 us; speedup 1.0000x reference)
//
#include <hip/hip_runtime.h>

#define LN_EPS 1e-5f

typedef float v4f __attribute__((ext_vector_type(4)));

constexpr int BLOCK = 512;            // 8 waves
constexpr int RPT   = 4;              // rows per lane
constexpr int WROWS = 64 * RPT;       // 256 rows per wave
constexpr int RPB   = BLOCK * RPT;    // 2048 rows per block

__global__ __launch_bounds__(BLOCK) void ln_linear_softmax_kernel(
    const v4f*   __restrict__ x,     // [n] rows of 4 floats
    const float* __restrict__ W,     // [4,3] row-major
    const float* __restrict__ gamma, // [4]
    const float* __restrict__ beta,  // [4]
    v4f*         __restrict__ out4,  // out viewed as float4 (n*3/4 elements)
    int n)
{
    __shared__ float lds[RPB * 3];    // 24 KB; 3 KB slice per wave

    const int  tid   = threadIdx.x;
    const int  wid   = tid >> 6;
    const int  lane  = tid & 63;
    const long base  = (long)blockIdx.x * RPB;
    const long wbase = base + (long)wid * WROWS;   // this wave's first row

    const v4f g = *(const v4f*)gamma;
    const v4f b = *(const v4f*)beta;
    const v4f* W4 = (const v4f*)W;
    const v4f w0 = W4[0]; // W00 W01 W02 W10
    const v4f w1 = W4[1]; // W11 W12 W20 W21
    const v4f w2 = W4[2]; // W22 W30 W31 W32

    float* wlds = &lds[wid * (WROWS * 3)];

    if (base + RPB <= (long)n) {
        // Hot path: wave-local packing, NO block barrier. Each wave packs
        // its own 256 rows into its own LDS slice and streams them out —
        // stores from leading waves overlap loads from lagging waves
        // (continuous R/W mix, like a copy kernel), instead of the
        // __syncthreads phase-split read-burst/write-burst oscillation.
        v4f v[RPT];
        #pragma unroll
        for (int k = 0; k < RPT; ++k)
            v[k] = __builtin_nontemporal_load(&x[wbase + lane + 64 * k]);

        #pragma unroll
        for (int k = 0; k < RPT; ++k) {
            const int rl = lane + 64 * k;
            v4f q = v[k];

            float mu = (q.x + q.y + q.z + q.w) * 0.25f;
            float dx = q.x - mu, dy = q.y - mu, dz = q.z - mu, dw = q.w - mu;
            float var = (dx*dx + dy*dy + dz*dz + dw*dw) * 0.25f;
            float rs  = rsqrtf(var + LN_EPS);

            float h0 = dx * rs * g.x + b.x;
            float h1 = dy * rs * g.y + b.y;
            float h2 = dz * rs * g.z + b.z;
            float h3 = dw * rs * g.w + b.w;

            float l0 = h0*w0.x + h1*w0.w + h2*w1.z + h3*w2.y;
            float l1 = h0*w0.y + h1*w1.x + h2*w1.w + h3*w2.z;
            float l2 = h0*w0.z + h1*w1.y + h2*w2.x + h3*w2.w;

            float m   = fmaxf(l0, fmaxf(l1, l2));
            float e0  = __expf(l0 - m);
            float e1  = __expf(l1 - m);
            float e2  = __expf(l2 - m);
            float inv = 1.0f / (e0 + e1 + e2);

            // dword stride 3 -> exactly 2 lanes/bank (free)
            wlds[rl*3 + 0] = e0 * inv;
            wlds[rl*3 + 1] = e1 * inv;
            wlds[rl*3 + 2] = e2 * inv;
        }

        // Wave-synchronous LDS RAW: drain ds_writes, forbid reordering.
        asm volatile("s_waitcnt lgkmcnt(0)" ::: "memory");

        // 192 packed float4s per wave, 16 B/lane dense — fully coalesced.
        const v4f* wlds4 = (const v4f*)wlds;
        const long ow4   = (wbase * 3) >> 2;   // wbase*3 is a multiple of 4
        #pragma unroll
        for (int k = 0; k < 3; ++k) {
            __builtin_nontemporal_store(wlds4[lane + 64 * k],
                                        &out4[ow4 + lane + 64 * k]);
        }
    } else {
        // Tail block (never hit for the bench shape): per-row scalar path.
        float* out = (float*)out4;
        for (int k = 0; k < RPT; ++k) {
            const long row = wbase + lane + 64 * k;
            if (row < n) {
                v4f q = __builtin_nontemporal_load(&x[row]);

                float mu = (q.x + q.y + q.z + q.w) * 0.25f;
                float dx = q.x - mu, dy = q.y - mu, dz = q.z - mu, dw = q.w - mu;
                float var = (dx*dx + dy*dy + dz*dz + dw*dw) * 0.25f;
                float rs  = rsqrtf(var + LN_EPS);

                float h0 = dx * rs * g.x + b.x;
                float h1 = dy * rs * g.y + b.y;
                float h2 = dz * rs * g.z + b.z;
                float h3 = dw * rs * g.w + b.w;

                float l0 = h0*w0.x + h1*w0.w + h2*w1.z + h3*w2.y;
                float l1 = h0*w0.y + h1*w1.x + h2*w1.w + h3*w2.z;
                float l2 = h0*w0.z + h1*w1.y + h2*w2.x + h3*w2.w;

                float m   = fmaxf(l0, fmaxf(l1, l2));
                float e0  = __expf(l0 - m);
                float e1  = __expf(l1 - m);
                float e2  = __expf(l2 - m);
                float inv = 1.0f / (e0 + e1 + e2);

                out[row*3 + 0] = e0 * inv;
                out[row*3 + 1] = e1 * inv;
                out[row*3 + 2] = e2 * inv;
            }
        }
    }
}

extern "C" void kernel_launch(void* const* d_in, const int* in_sizes, int n_in,
                              void* d_out, int out_size, void* d_ws, size_t ws_size,
                              hipStream_t stream) {
    const float* x     = (const float*)d_in[0];
    const float* W     = (const float*)d_in[1];
    const float* gamma = (const float*)d_in[2];
    const float* beta  = (const float*)d_in[3];
    v4f* out4 = (v4f*)d_out;

    int n = in_sizes[0] / 4;                 // number of rows (8,388,608)
    int grid = (n + RPB - 1) / RPB;          // 4096 blocks
    ln_linear_softmax_kernel<<<grid, BLOCK, 0, stream>>>(
        (const v4f*)x, W, gamma, beta, out4, n);
}